// Round 14
// baseline (101.044 us; speedup 1.0000x reference)
//
#include <hip/hip_runtime.h>

#define DD_   41
#define FH_   8
#define FW_   22
#define NPIX  176
#define C_    64
#define NXX   200
#define NXY   200
#define NCHUNK 5             // ix chunks of 40 rows
#define CHROWS 40
#define CPLANE (CHROWS*NXY)  // 8000 floats = 32 KB contiguous write per channel
#define NRAY  150            // 6 cams x 25 active pixels
#define NITEM (NRAY*DD_)     // 6150
#define CGRP  8              // channel groups in grid
#define CPB   (C_/CGRP)      // 8 channels per block

// ONE dispatch. Grid (chunk, cgroup, b) = 5x8x8 = 320 blocks, 2/CU co-resident.
// Per block: f64 geometry ONCE (150 rays, chains verbatim from passing R13),
// all 6150 items evaluated ONCE into LDS (vloc short + wgt f32), then 8 channels:
// zero tile -> walk cached items (no f64) -> one contiguous 32 KB store.
__global__ __launch_bounds__(256, 4) void fused3(
    const float* __restrict__ depth_logits,
    const float* __restrict__ feats,
    const float* __restrict__ rots,
    const float* __restrict__ trans,
    const float* __restrict__ Kp,
    const float* __restrict__ Dc,
    const float* __restrict__ xip,
    float* __restrict__ out)
{
#pragma clang fp contract(off)
    const int chunk = blockIdx.x;        // 0..4
    const int cgrp  = blockIdx.y;        // 0..7
    const int b     = blockIdx.z;        // 0..7
    const int t     = threadIdx.x;
    const int ix0   = chunk * CHROWS;

    __shared__ float  tile[CPLANE];          // 32000 B
    __shared__ float  wgt_lds[NITEM];        // 24600 B
    __shared__ short  vloc_lds[NITEM];       // 12300 B
    __shared__ double axl[NRAY], ayl[NRAY], azl[NRAY];   // 3600 B
    __shared__ float  mxl[NRAY], ssl[NRAY], f_l[NRAY];   // 1800 B
    __shared__ int    pixl[NRAY];            // 600 B   (total ~74.9 KB)

    // ================= RAY PHASE (threads 0..149) — chains verbatim =================
    if (t < NRAY) {
        const int cam = b * 6 + t / 25;
        const int j   = t % 25;
        const double u0 = (double)Kp[cam * 4 + 2];
        const double v0 = (double)Kp[cam * 4 + 3];
        const int u0m = (int)floor(u0 / 16.0);
        const int v0m = (int)floor(v0 / 16.0);
        const int dx = j % 5 - 2, dy = j / 5 - 2;
        const int w = u0m + dx, h = v0m + dy;
        const bool ok = (dx * dx + dy * dy < 9) & (w >= 0) & (w < FW_) & (h >= 0) & (h < FH_);
        pixl[t] = ok ? h * FW_ + w : -1;
        if (ok) {
            const int pix = h * FW_ + w;
            const double g1 = (double)Kp[cam * 4 + 0];
            const double g2 = (double)Kp[cam * 4 + 1];
            const double k1 = (double)Dc[cam * 4 + 0];
            const double k2 = (double)Dc[cam * 4 + 1];
            const double p1 = (double)Dc[cam * 4 + 2];
            const double p2 = (double)Dc[cam * 4 + 3];
            const double xiv = (double)xip[cam];

            const double px = (double)w * (351.0 / 21.0);
            const double py = (double)h * (127.0 / 7.0);
            const double ppx = (px - u0) / g1;
            const double ppy = (py - v0) / g2;
            double pux = ppx, puy = ppy;
            for (int it = 0; it < 20; ++it) {
                double r2 = pux * pux + puy * puy;
                double r4 = r2 * r2;
                double denom = 1.0 + k1 * r2 + k2 * r4;
                double nx_ = (ppx - 2.0 * p1 * pux * puy - p2 * (r2 + 2.0 * pux * pux)) / denom;
                double ny_ = (ppy - 2.0 * p2 * pux * puy - p1 * (r2 + 2.0 * puy * puy)) / denom;
                pux = nx_; puy = ny_;
            }
            double r2 = pux * pux + puy * puy;
            double aq = r2 + 1.0;
            double bq = 2.0 * xiv * r2;
            double cq = xiv * xiv * r2 - 1.0;
            double Zs = (-bq + sqrt(bq * bq - 4.0 * aq * cq)) / (2.0 * aq);
            double rx = pux * (Zs + xiv);
            double ry = puy * (Zs + xiv);
            double rz = Zs;
            double nrm = sqrt(rx * rx + ry * ry + rz * rz);
            rx /= nrm; ry /= nrm; rz /= nrm;

            const float* lg = depth_logits + (size_t)cam * DD_ * NPIX + pix;
            float mxv = -3.0e38f;
            #pragma unroll
            for (int d = 0; d < DD_; ++d) mxv = fmaxf(mxv, lg[d * NPIX]);
            float ssum = 0.0f;
            #pragma unroll
            for (int d = 0; d < DD_; ++d) ssum += expf(lg[d * NPIX] - mxv);
            mxl[t] = mxv; ssl[t] = ssum;

            const float* R = rots + (size_t)cam * 9;
            axl[t] = (double)R[0] * rx + (double)R[1] * ry + (double)R[2] * rz;
            ayl[t] = (double)R[3] * rx + (double)R[4] * ry + (double)R[5] * rz;
            azl[t] = (double)R[6] * rx + (double)R[7] * ry + (double)R[8] * rz;
        }
    }
    __syncthreads();

    // ================= ITEM PHASE: evaluate all 6150 items once =================
    int myhit = 0;
    for (int q = t; q < NITEM; q += 256) {
        const int s = q / DD_, d = q - s * DD_;
        const int cam = b * 6 + s / 25;
        const int pix = pixl[s];
        short v = -1; float wgt = 0.0f;
        if (pix >= 0) {
            const double dval = 4.0 + (double)d;
            const double ex = axl[s] * dval + (double)trans[cam * 3 + 0];
            const double ey = ayl[s] * dval + (double)trans[cam * 3 + 1];
            const double ez = azl[s] * dval + (double)trans[cam * 3 + 2];
            const double sx = -ex, sy = ey, sz = ez;    // * [-1,1,1]
            const int ix = (int)floor((sx + 50.0) / 0.5);
            const int iy = (int)floor((sy + 50.0) / 0.5);
            const int iz = (int)floor((sz + 10.0) / 20.0);
            if (((unsigned)(ix - ix0) < (unsigned)CHROWS) & ((unsigned)iy < (unsigned)NXY) & (iz == 0)) {
                const float lgv = depth_logits[((size_t)cam * DD_ + d) * NPIX + pix];
                wgt = expf(lgv - mxl[s]) / ssl[s];
                v = (short)((ix - ix0) * NXY + iy);
                myhit = 1;
            }
        }
        vloc_lds[q] = v; wgt_lds[q] = wgt;
    }
    const int nh = __syncthreads_count(myhit);

    float* ob0 = out + (size_t)(b * C_ + cgrp * CPB) * (NXX * NXY) + (size_t)ix0 * NXY;

    if (nh == 0) {   // chunk unreachable: 8 contiguous 32 KB zero runs
        const float4 z = make_float4(0.f, 0.f, 0.f, 0.f);
        for (int cg = 0; cg < CPB; ++cg) {
            float* ob = ob0 + (size_t)cg * (NXX * NXY);
            for (int i4 = t; i4 < CPLANE / 4; i4 += 256)
                ((float4*)ob)[i4] = z;
        }
        return;
    }

    // ================= CHANNEL LOOP: 8 channels, no f64 =================
    for (int cg = 0; cg < CPB; ++cg) {
        const int c = cgrp * CPB + cg;
        if (t < NRAY) {
            const int cam = b * 6 + t / 25;
            f_l[t] = (pixl[t] >= 0)
                   ? feats[((size_t)cam * C_ + c) * NPIX + pixl[t]] : 0.0f;
        }
        for (int i4 = t; i4 < CPLANE / 4; i4 += 256)
            ((float4*)tile)[i4] = make_float4(0.f, 0.f, 0.f, 0.f);
        __syncthreads();

        for (int q = t; q < NITEM; q += 256) {
            const short v = vloc_lds[q];
            if (v >= 0) atomicAdd(&tile[v], wgt_lds[q] * f_l[q / DD_]);
        }
        __syncthreads();

        float* ob = ob0 + (size_t)cg * (NXX * NXY);
        for (int i4 = t; i4 < CPLANE / 4; i4 += 256)
            ((float4*)ob)[i4] = *(const float4*)&tile[i4 * 4];
        __syncthreads();
    }
}

extern "C" void kernel_launch(void* const* d_in, const int* in_sizes, int n_in,
                              void* d_out, int out_size, void* d_ws, size_t ws_size,
                              hipStream_t stream) {
    const float* depth_logits = (const float*)d_in[0];
    const float* feats        = (const float*)d_in[1];
    const float* rots         = (const float*)d_in[2];
    const float* trans        = (const float*)d_in[3];
    const float* Kp           = (const float*)d_in[4];
    const float* Dc           = (const float*)d_in[5];
    const float* xip          = (const float*)d_in[6];
    float* out = (float*)d_out;

    fused3<<<dim3(NCHUNK, CGRP, 8), dim3(256), 0, stream>>>(
        depth_logits, feats, rots, trans, Kp, Dc, xip, out);
}

// Round 16
// 45.288 us; speedup vs baseline: 2.2311x; 2.2311x over previous
//
#include <hip/hip_runtime.h>

#define DD_   41
#define FH_   8
#define FW_   22
#define NPIX  176
#define C_    64
#define NXX   200
#define NXY   200
#define NCAM  48
#define NCHUNK 5             // ix chunks of 40 rows
#define CHROWS 40
#define CAPCH  640           // records per (camera,chunk); geometric bound ~525
#define CPLANE (CHROWS*NXY)  // 8000 floats = 32000 B contiguous
#define NACT  25             // active pixels per camera (5x5 disc)
#define NSTAGE (NACT*DD_)    // 1025 fixed staging slots

typedef float vf4 __attribute__((ext_vector_type(4)));   // native vec: NT-store OK

// ---- K01: one block per camera (identical to passing R9) ----
__global__ __launch_bounds__(256) void k01_prep(
    const float* __restrict__ depth_logits,
    const float* __restrict__ rots,
    const float* __restrict__ trans,
    const float* __restrict__ Kp,
    const float* __restrict__ Dc,
    const float* __restrict__ xip,
    int* __restrict__ cnt_cam,
    uint2* __restrict__ bucketed)
{
#pragma clang fp contract(off)
    const int cam = blockIdx.x;
    const int t = threadIdx.x;

    __shared__ uint2 rec_stage[NSTAGE];
    __shared__ double rayx[NACT], rayy[NACT], rayz[NACT];
    __shared__ float mx_l[NACT], ss_l[NACT];
    __shared__ int pix_l[NACT];
    __shared__ int cur_lds[NCHUNK];

    for (int i = t; i < NSTAGE; i += 256) rec_stage[i] = make_uint2(0xFFFFFFFFu, 0u);
    if (t < NCHUNK) cur_lds[t] = 0;

    if (t < NACT) {
        const double u0 = (double)Kp[cam * 4 + 2];
        const double v0 = (double)Kp[cam * 4 + 3];
        const int u0m = (int)floor(u0 / 16.0);
        const int v0m = (int)floor(v0 / 16.0);
        const int dx = t % 5 - 2, dy = t / 5 - 2;
        const int w = u0m + dx, h = v0m + dy;
        const bool ok = (dx * dx + dy * dy < 9) & (w >= 0) & (w < FW_) & (h >= 0) & (h < FH_);
        pix_l[t] = ok ? h * FW_ + w : -1;
        if (ok) {
            const int pix = h * FW_ + w;
            const double g1 = (double)Kp[cam * 4 + 0];
            const double g2 = (double)Kp[cam * 4 + 1];
            const double k1 = (double)Dc[cam * 4 + 0];
            const double k2 = (double)Dc[cam * 4 + 1];
            const double p1 = (double)Dc[cam * 4 + 2];
            const double p2 = (double)Dc[cam * 4 + 3];
            const double xiv = (double)xip[cam];

            const double px = (double)w * (351.0 / 21.0);
            const double py = (double)h * (127.0 / 7.0);
            const double ppx = (px - u0) / g1;
            const double ppy = (py - v0) / g2;
            double pux = ppx, puy = ppy;
            for (int it = 0; it < 20; ++it) {
                double r2 = pux * pux + puy * puy;
                double r4 = r2 * r2;
                double denom = 1.0 + k1 * r2 + k2 * r4;
                double nx_ = (ppx - 2.0 * p1 * pux * puy - p2 * (r2 + 2.0 * pux * pux)) / denom;
                double ny_ = (ppy - 2.0 * p2 * pux * puy - p1 * (r2 + 2.0 * puy * puy)) / denom;
                pux = nx_; puy = ny_;
            }
            double r2 = pux * pux + puy * puy;
            double aq = r2 + 1.0;
            double bq = 2.0 * xiv * r2;
            double cq = xiv * xiv * r2 - 1.0;
            double Zs = (-bq + sqrt(bq * bq - 4.0 * aq * cq)) / (2.0 * aq);
            double rx = pux * (Zs + xiv);
            double ry = puy * (Zs + xiv);
            double rz = Zs;
            double nrm = sqrt(rx * rx + ry * ry + rz * rz);
            rayx[t] = rx / nrm; rayy[t] = ry / nrm; rayz[t] = rz / nrm;

            const float* lg = depth_logits + (size_t)cam * DD_ * NPIX + pix;
            float mxv = -3.0e38f;
            #pragma unroll
            for (int d = 0; d < DD_; ++d) mxv = fmaxf(mxv, lg[d * NPIX]);
            float ssum = 0.0f;
            #pragma unroll
            for (int d = 0; d < DD_; ++d) ssum += expf(lg[d * NPIX] - mxv);
            mx_l[t] = mxv; ss_l[t] = ssum;
        }
    }
    __syncthreads();

    {
        const int n = cam % 6;
        const float* R = rots + (size_t)cam * 9;
        const double R0 = (double)R[0], R1 = (double)R[1], R2 = (double)R[2];
        const double R3 = (double)R[3], R4 = (double)R[4], R5 = (double)R[5];
        const double R6 = (double)R[6], R7 = (double)R[7], R8 = (double)R[8];
        const double T0 = (double)trans[cam * 3 + 0];
        const double T1 = (double)trans[cam * 3 + 1];
        const double T2 = (double)trans[cam * 3 + 2];
        for (int i = t; i < NSTAGE; i += 256) {
            const int s = i / DD_, d = i - s * DD_;
            const int pix = pix_l[s];
            if (pix < 0) continue;
            const float lgv = depth_logits[((size_t)cam * DD_ + d) * NPIX + pix];
            const float wgt = expf(lgv - mx_l[s]) / ss_l[s];
            const double dval = 4.0 + (double)d;
            const double pcx = rayx[s] * dval, pcy = rayy[s] * dval, pcz = rayz[s] * dval;
            const double ex = R0 * pcx + R1 * pcy + R2 * pcz + T0;
            const double ey = R3 * pcx + R4 * pcy + R5 * pcz + T1;
            const double ez = R6 * pcx + R7 * pcy + R8 * pcz + T2;
            const double sx = -ex, sy = ey, sz = ez;   // * [-1,1,1]
            const int ix = (int)floor((sx + 50.0) / 0.5);
            const int iy = (int)floor((sy + 50.0) / 0.5);
            const int iz = (int)floor((sz + 10.0) / 20.0);
            if ((ix >= 0) & (ix < NXX) & (iy >= 0) & (iy < NXY) & (iz == 0)) {
                unsigned meta = (unsigned)iy | ((unsigned)ix << 8)
                              | ((unsigned)pix << 16) | ((unsigned)n << 24);
                rec_stage[i] = make_uint2(meta, __float_as_uint(wgt));
            }
        }
    }
    __syncthreads();

    for (int i = t; i < NSTAGE; i += 256) {
        uint2 r = rec_stage[i];
        if (r.x != 0xFFFFFFFFu) {
            int chunk = (int)((r.x >> 8) & 255u) / CHROWS;
            int pos = atomicAdd(&cur_lds[chunk], 1);
            if (pos < CAPCH)
                bucketed[((size_t)cam * NCHUNK + chunk) * CAPCH + pos] = r;
        }
    }
    __syncthreads();
    if (t < NCHUNK) cnt_cam[cam * NCHUNK + t] = min(cur_lds[t], CAPCH);
}

// ---- K2: identical structure to passing R9, but ALL output stores are
//      NON-TEMPORAL (streaming; bypass L2 write-allocate).
__global__ __launch_bounds__(256) void k2_splat(
    const uint2* __restrict__ bucketed,
    const int* __restrict__ cnt_cam,
    const float* __restrict__ feats,
    float* __restrict__ out)
{
    const int chunk = blockIdx.x;  // 0..4
    const int c     = blockIdx.y;  // 0..63
    const int b     = blockIdx.z;  // 0..7
    const int tid = threadIdx.x;
    const int ix0 = chunk * CHROWS;

    int nr[6], maxnr = 0;
    #pragma unroll
    for (int n = 0; n < 6; ++n) {
        int v = cnt_cam[(b * 6 + n) * NCHUNK + chunk];
        nr[n] = v < CAPCH ? v : CAPCH;
        maxnr = nr[n] > maxnr ? nr[n] : maxnr;
    }

    vf4* ob4 = (vf4*)(out + (size_t)(b * C_ + c) * (NXX * NXY) + (size_t)ix0 * NXY);

    if (maxnr == 0) {   // contiguous 32 KB zero run, streaming stores
        const vf4 z = (vf4){0.f, 0.f, 0.f, 0.f};
        for (int i4 = tid; i4 < CPLANE / 4; i4 += 256)
            __builtin_nontemporal_store(z, ob4 + i4);
        return;
    }

    __shared__ float tile[CPLANE];
    for (int i4 = tid; i4 < CPLANE / 4; i4 += 256)
        ((vf4*)tile)[i4] = (vf4){0.f, 0.f, 0.f, 0.f};
    __syncthreads();

    for (int q = tid; q < maxnr; q += 256) {
        #pragma unroll
        for (int n = 0; n < 6; ++n) {
            if (q < nr[n]) {
                uint2 r = bucketed[((size_t)(b * 6 + n) * NCHUNK + chunk) * CAPCH + q];
                int iy = r.x & 255, ix = (r.x >> 8) & 255;
                int hw = (r.x >> 16) & 255;
                float wgt = __uint_as_float(r.y);
                float f = feats[((size_t)(b * 6 + n) * C_ + c) * NPIX + hw];
                atomicAdd(&tile[(ix - ix0) * NXY + iy], wgt * f);
            }
        }
    }
    __syncthreads();

    for (int i4 = tid; i4 < CPLANE / 4; i4 += 256)
        __builtin_nontemporal_store(((const vf4*)tile)[i4], ob4 + i4);
}

extern "C" void kernel_launch(void* const* d_in, const int* in_sizes, int n_in,
                              void* d_out, int out_size, void* d_ws, size_t ws_size,
                              hipStream_t stream) {
    const float* depth_logits = (const float*)d_in[0];
    const float* feats        = (const float*)d_in[1];
    const float* rots         = (const float*)d_in[2];
    const float* trans        = (const float*)d_in[3];
    const float* Kp           = (const float*)d_in[4];
    const float* Dc           = (const float*)d_in[5];
    const float* xip          = (const float*)d_in[6];
    float* out = (float*)d_out;

    char* ws = (char*)d_ws;
    int*   cnt_cam  = (int*)ws;                        ws += 8192;  // 48*5*4 = 960 used
    uint2* bucketed = (uint2*)ws;                      // 48*5*640*8 = 1.23 MB

    k01_prep<<<dim3(NCAM), dim3(256), 0, stream>>>(depth_logits, rots, trans,
                                                   Kp, Dc, xip, cnt_cam, bucketed);
    k2_splat<<<dim3(NCHUNK, C_, 8), dim3(256), 0, stream>>>(bucketed, cnt_cam, feats, out);
}